// Round 8
// baseline (128.534 us; speedup 1.0000x reference)
//
#include <hip/hip_runtime.h>
#include <math.h>

#define SN  512
#define NN  128
#define CIN 32
#define CA  5
#define HH  64
#define YY  96
#define H3  128
#define H4  64
#define EPSF 1e-7f

typedef __attribute__((ext_vector_type(8))) short  bf16x8;
typedef __attribute__((ext_vector_type(4))) float  f32x4;
typedef __attribute__((ext_vector_type(4))) unsigned short us4;

__device__ inline unsigned short f2b(float f) {
    unsigned u = __builtin_bit_cast(unsigned, f);
    return (unsigned short)((u + 0x7FFFu + ((u >> 16) & 1u)) >> 16);
}
__device__ inline float b2f(unsigned short h) {
    unsigned u = ((unsigned)h) << 16;
    return __builtin_bit_cast(float, u);
}
__device__ inline bf16x8 pack8(float4 f0, float4 f1) {
    bf16x8 v;
    v[0]=(short)f2b(f0.x); v[1]=(short)f2b(f0.y); v[2]=(short)f2b(f0.z); v[3]=(short)f2b(f0.w);
    v[4]=(short)f2b(f1.x); v[5]=(short)f2b(f1.y); v[6]=(short)f2b(f1.z); v[7]=(short)f2b(f1.w);
    return v;
}

// PZ: 256 rows (c0..c3 x 64 b) x 128 shorts, XOR-swizzled 16B chunks.
__device__ inline void pz_store4(short* PZ, int row, int colsh, const f32x4& pc) {
    int byo = (colsh*2) ^ ((row & 7) << 4);
    us4 w;
    w[0]=f2b(pc[0]); w[1]=f2b(pc[1]); w[2]=f2b(pc[2]); w[3]=f2b(pc[3]);
    *(us4*)&PZ[row*128 + (byo >> 1)] = w;
}
__device__ inline bf16x8 pz_load8(const short* PZ, int row, int colsh) {
    int byo = (colsh*2) ^ ((row & 7) << 4);
    return *(const bf16x8*)&PZ[row*128 + (byo >> 1)];
}
// PART (bf16): [p][i=16][b=64] with kg-rotation on b for bank spread.
__device__ inline int part_idx(int p, int ir, int col, int kg) {
    return p*1024 + ir*64 + ((col + kg*16) & 63);
}

// ws pack (bf16): W1p [c5][b64][a32] @0 | W2p [c5][b64][a96] @10240 | nwp [b128][a96] @40960
__global__ __launch_bounds__(512) void pack_weights(
    const float* __restrict__ w1, const float* __restrict__ lw1,
    const float* __restrict__ w2, const float* __restrict__ lw2,
    const float* __restrict__ nw, unsigned short* __restrict__ wp)
{
    int t = blockIdx.x*512 + threadIdx.x;
    if (t < 10240) {
        int c = t >> 11, rem = t & 2047, b = rem >> 5, a = rem & 31;
        float v = (c < 4) ? w1[(a*64+b)*4 + c] : lw1[a*64+b];
        wp[t] = f2b(v);
    } else if (t < 40960) {
        int u = t - 10240;
        int c = u / 6144, rem = u % 6144, b = rem / 96, a = rem % 96;
        float v = (c < 4) ? w2[(a*64+b)*4 + c] : lw2[a*64+b];
        wp[t] = f2b(v);
    } else {
        int u = t - 40960;
        int b = u / 96, a = u % 96;
        wp[t] = f2b(nw[a*128 + b]);
    }
}

// Conv stage, c-split wave pairs: wave (p,h): h0 -> P c{0,1}, main c{0,1}, combine;
// h1 -> P c{2,3,4} (c4 -> PART), main c{2,3}, epilogue RMW PART += acc*inv.
template<int CINY, bool FIRST>
__device__ __forceinline__ void conv_core(
    const unsigned short* __restrict__ wp, const float* __restrict__ LB,
    short* PZ, unsigned short* PART, const bf16x8 (&Af)[4][2],
    bf16x8 y0, bf16x8 y1, bf16x8 y2,
    float (&inv)[2][4], float (&v)[4][4],
    int p, int h, int lm, int kg)
{
    constexpr int K32  = CINY / 32;
    constexpr int WOFF = (CINY == 32) ? 0 : 10240;
    bf16x8 yf[3] = {y0, y1, y2};

    #pragma unroll
    for (int cl = 0; cl < 3; ++cl) {
        if (!h && cl == 2) continue;
        const int c = h ? 2 + cl : cl;
        f32x4 pc[4];
        #pragma unroll
        for (int n = 0; n < 4; ++n) pc[n] = (f32x4){0.f,0.f,0.f,0.f};
        #pragma unroll
        for (int ks = 0; ks < K32; ++ks) {
            #pragma unroll
            for (int n = 0; n < 4; ++n) {
                const bf16x8 bw = *(const bf16x8*)&wp[WOFF + (c*64 + n*16 + lm)*CINY + ks*32 + kg*8];
                pc[n] = __builtin_amdgcn_mfma_f32_16x16x32_bf16(yf[ks], bw, pc[n], 0,0,0);
            }
        }
        if (c < 4) {
            #pragma unroll
            for (int n = 0; n < 4; ++n)
                pz_store4(PZ, c*64 + n*16 + lm, p*16 + kg*4, pc[n]);
        } else {
            #pragma unroll
            for (int n = 0; n < 4; ++n)
                #pragma unroll
                for (int r = 0; r < 4; ++r)
                    PART[part_idx(p, kg*4+r, n*16+lm, kg)] = f2b(pc[n][r]);
        }
    }
    __syncthreads();

    f32x4 acc[2][4];
    #pragma unroll
    for (int cl=0;cl<2;++cl)
        #pragma unroll
        for (int n=0;n<4;++n) acc[cl][n] = (f32x4){0.f,0.f,0.f,0.f};
    f32x4 sums[2];
    if constexpr (FIRST) {
        #pragma unroll
        for (int cl=0;cl<2;++cl) sums[cl] = (f32x4){0.f,0.f,0.f,0.f};
    }
    bf16x8 ones;
    #pragma unroll
    for (int q=0;q<8;++q) ones[q] = (short)0x3F80;

    #pragma unroll
    for (int jt = 0; jt < 4; ++jt) {
        #pragma unroll
        for (int cl = 0; cl < 2; ++cl) {
            const int row0 = (2*h + cl)*64;
            #pragma unroll
            for (int n = 0; n < 4; ++n) {
                const bf16x8 bp = pz_load8(PZ, row0 + n*16 + lm, jt*32 + kg*8);
                acc[cl][n] = __builtin_amdgcn_mfma_f32_16x16x32_bf16(Af[jt][cl], bp, acc[cl][n], 0,0,0);
            }
            if constexpr (FIRST)
                sums[cl] = __builtin_amdgcn_mfma_f32_16x16x32_bf16(Af[jt][cl], ones, sums[cl], 0,0,0);
        }
    }
    if constexpr (FIRST) {
        #pragma unroll
        for (int cl=0;cl<2;++cl)
            #pragma unroll
            for (int r=0;r<4;++r) inv[cl][r] = 1.0f/(sums[cl][r] + EPSF);
    }

    if (h) {   // fold channels {2,3} into PART (which already holds P4)
        #pragma unroll
        for (int n=0;n<4;++n)
            #pragma unroll
            for (int r=0;r<4;++r) {
                const int idx = part_idx(p, kg*4+r, n*16+lm, kg);
                float pv = b2f(PART[idx])
                         + acc[0][n][r]*inv[0][r] + acc[1][n][r]*inv[1][r];
                PART[idx] = f2b(pv);
            }
    }
    __syncthreads();
    if (!h) {  // combine: own {0,1} + PART(= c2,c3,linear) + bias, tanh
        #pragma unroll
        for (int n=0;n<4;++n) {
            const float lbv = LB[n*16 + lm];
            #pragma unroll
            for (int r=0;r<4;++r) {
                float vv = lbv
                    + acc[0][n][r]*inv[0][r] + acc[1][n][r]*inv[1][r]
                    + b2f(PART[part_idx(p, kg*4+r, n*16+lm, kg)]);
                v[n][r] = tanhf(vv);
            }
        }
    }
}

__global__ __launch_bounds__(1024, 8) void fused_kernel(
    const float* __restrict__ A, const float* __restrict__ x,
    const unsigned short* __restrict__ wp,
    const float* __restrict__ lb1, const float* __restrict__ lb2,
    const float* __restrict__ gw, const float* __restrict__ gb,
    const float* __restrict__ nb,
    const float* __restrict__ l3w, const float* __restrict__ l3b,
    const float* __restrict__ l4w, const float* __restrict__ l4b,
    const float* __restrict__ l5w, const float* __restrict__ l5b,
    float* __restrict__ out)
{
    __shared__ __align__(16) char smem[81920];
    short* PZ = (short*)smem;                             // 256x128 sh = 65536 B
    unsigned short* PART = (unsigned short*)(smem + 65536); // 8192 sh = 16384 B
    short* H1  = (short*)smem;                            // [128][72] sh (PZ alias)
    short* xcb = (short*)smem;                            // [128][104] sh (PZ alias)
    float* part = (float*)(smem + 65536);                 // [16][128] f32 (PART alias)
    float* gate = (float*)(smem + 65536 + 8192);          // 512 B
    float* red  = (float*)(smem + 65536 + 8704);          // 512 B
    float* tmpv = (float*)(smem + 65536 + 9216);          // 512 B

    const int s = blockIdx.x, tid = threadIdx.x;
    const int wave = tid>>6, lane = tid&63, lm = lane&15, kg = lane>>4;
    const int p = wave >> 1, h = wave & 1;
    const float* xg = x + (size_t)s*NN*CIN;

    const int jrow = p*16 + lm;
    bf16x8 xfrag;
    {
        float4 f0 = *(const float4*)(xg + jrow*CIN + kg*8);
        float4 f1 = *(const float4*)(xg + jrow*CIN + kg*8 + 4);
        xfrag = pack8(f0, f1);
    }

    // ===== A prepass: coalesced float4 -> pair-shared LDS (single buf) -> Af =====
    bf16x8 Af[4][2];
    {
        const float* Ab = A + ((size_t)s*NN + p*16)*NN*CA;
        const int r8 = lane>>3, l8 = lane&7;
        const int rr = r8 + 8*h;
        #pragma unroll
        for (int jt = 0; jt < 4; ++jt) {
            short* buf = (short*)smem + p*2688;           // [16][168]
            {
                const float* rp = Ab + (size_t)rr*(NN*CA) + jt*160 + l8*20;
                float4 q0 = *(const float4*)(rp);
                float4 q1 = *(const float4*)(rp+4);
                float4 q2 = *(const float4*)(rp+8);
                float4 q3 = *(const float4*)(rp+12);
                float4 q4 = *(const float4*)(rp+16);
                short* lr = buf + rr*168;
                const int jb = 4*l8;
                lr[0*40 + jb+0] = (short)f2b(q0.x);
                lr[1*40 + jb+0] = (short)f2b(q0.y);
                lr[2*40 + jb+0] = (short)f2b(q0.z);
                lr[3*40 + jb+0] = (short)f2b(q0.w);
                lr[0*40 + jb+1] = (short)f2b(q1.y);
                lr[1*40 + jb+1] = (short)f2b(q1.z);
                lr[2*40 + jb+1] = (short)f2b(q1.w);
                lr[3*40 + jb+1] = (short)f2b(q2.x);
                lr[0*40 + jb+2] = (short)f2b(q2.z);
                lr[1*40 + jb+2] = (short)f2b(q2.w);
                lr[2*40 + jb+2] = (short)f2b(q3.x);
                lr[3*40 + jb+2] = (short)f2b(q3.y);
                lr[0*40 + jb+3] = (short)f2b(q3.w);
                lr[1*40 + jb+3] = (short)f2b(q4.x);
                lr[2*40 + jb+3] = (short)f2b(q4.y);
                lr[3*40 + jb+3] = (short)f2b(q4.z);
            }
            __syncthreads();
            #pragma unroll
            for (int cl = 0; cl < 2; ++cl)
                Af[jt][cl] = *(const bf16x8*)&buf[lm*168 + (2*h + cl)*40 + kg*8];
            __syncthreads();
        }
    }

    // ===== conv1 =====
    float inv[2][4];
    float v[4][4];
    conv_core<CIN, true>(wp, lb1, PZ, PART, Af, xfrag, xfrag, xfrag,
                         inv, v, p, h, lm, kg);
    if (!h) {  // h1 result -> H1 (PZ region dead: all PZ reads done pre-epilogue bar)
        #pragma unroll
        for (int n=0;n<4;++n)
            #pragma unroll
            for (int r=0;r<4;++r)
                H1[(p*16 + kg*4 + r)*72 + n*16 + lm] = (short)f2b(v[n][r]);
    }
    __syncthreads();   // H1 visible

    // ===== conv2 =====
    {
        bf16x8 h0f = *(const bf16x8*)&H1[jrow*72 + kg*8];
        bf16x8 h1f = *(const bf16x8*)&H1[jrow*72 + 32 + kg*8];
        __syncthreads();   // H1 reads done -> PZ writable
        conv_core<YY, false>(wp, lb2, PZ, PART, Af, h0f, h1f, xfrag,
                             inv, v, p, h, lm, kg);
    }

    // ===== pool + head =====
    if (!h) {
        #pragma unroll
        for (int n=0;n<4;++n)
            #pragma unroll
            for (int r=0;r<4;++r)
                xcb[(p*16 + kg*4 + r)*104 + n*16 + lm] = (short)f2b(v[n][r]);
    }
    for (int t = tid; t < NN*CIN; t += 1024)
        xcb[(t>>5)*104 + 64 + (t&31)] = (short)f2b(xg[t]);
    __syncthreads();

    // gate logits: 8 threads per node
    {
        const int i = tid >> 3, t8 = tid & 7;
        float z = 0.f;
        #pragma unroll
        for (int q = 0; q < 12; ++q) {
            const int a = t8*12 + q;
            z += b2f((unsigned short)xcb[i*104 + a]) * gw[a];
        }
        z += __shfl_xor(z, 1); z += __shfl_xor(z, 2); z += __shfl_xor(z, 4);
        if (t8 == 0) red[i] = z + gb[0];
    }
    __syncthreads();
    if (wave == 0) {   // softmax over 128 nodes, one wave
        float v0 = red[lane], v1 = red[lane + 64];
        float m = fmaxf(v0, v1);
        #pragma unroll
        for (int off = 32; off > 0; off >>= 1) m = fmaxf(m, __shfl_xor(m, off));
        float e0 = expf(v0 - m), e1 = expf(v1 - m);
        float ssum = e0 + e1;
        #pragma unroll
        for (int off = 32; off > 0; off >>= 1) ssum += __shfl_xor(ssum, off);
        gate[lane] = e0 / ssum; gate[lane + 64] = e1 / ssum;
    }
    __syncthreads();

    // pooled GEMM: i-tile = p, halves split the 8 column tiles
    {
        f32x4 pacc[4];
        #pragma unroll
        for (int nt=0;nt<4;++nt) pacc[nt] = (f32x4){0.f,0.f,0.f,0.f};
        #pragma unroll
        for (int ks=0;ks<3;++ks) {
            const bf16x8 afp = *(const bf16x8*)&xcb[(p*16+lm)*104 + ks*32 + kg*8];
            #pragma unroll
            for (int nt=0;nt<4;++nt) {
                const int ntg = h*4 + nt;
                const bf16x8 bfp = *(const bf16x8*)&wp[40960 + (ntg*16+lm)*96 + ks*32 + kg*8];
                pacc[nt] = __builtin_amdgcn_mfma_f32_16x16x32_bf16(afp, bfp, pacc[nt], 0,0,0);
            }
        }
        #pragma unroll
        for (int nt=0;nt<4;++nt) {
            const int ntg = h*4 + nt;
            const float nbv = nb[ntg*16+lm];
            float pv = 0.f;
            #pragma unroll
            for (int r=0;r<4;++r)
                pv += gate[p*16 + kg*4 + r] * tanhf(pacc[nt][r] + nbv);
            pv += __shfl_xor(pv, 16);
            pv += __shfl_xor(pv, 32);
            if (lane < 16) part[wave*128 + ntg*16 + lm] = pv;
        }
    }
    __syncthreads();
    if (tid < H3) {
        // wave (p,h) wrote only columns [h*64, h*64+64) of its part row;
        // for column tid only rows with h == (tid>>6) are valid.
        const int ht = tid >> 6;
        float pooled = 0.f;
        #pragma unroll
        for (int pp = 0; pp < 8; ++pp) pooled += part[(pp*2 + ht)*128 + tid];
        tmpv[tid] = tanhf(pooled);                 // h3
    }
    __syncthreads();
    if (tid < H3) {
        float a4 = l3b[tid];
        for (int aa = 0; aa < H3; ++aa) a4 += tmpv[aa] * l3w[aa*H3 + tid];
        red[tid] = tanhf(a4);                      // h4
    }
    __syncthreads();
    if (tid < H4) {
        float a5 = l4b[tid];
        for (int aa = 0; aa < H3; ++aa) a5 += red[aa] * l4w[aa*H4 + tid];
        gate[tid] = tanhf(a5);                     // h5
    }
    __syncthreads();
    if (tid == 0) {
        float zo = l5b[0];
        for (int aa = 0; aa < H4; ++aa) zo += gate[aa] * l5w[aa];
        out[s] = 1.0f / (1.0f + expf(-zo));
    }
}

extern "C" void kernel_launch(void* const* d_in, const int* in_sizes, int n_in,
                              void* d_out, int out_size, void* d_ws, size_t ws_size,
                              hipStream_t stream)
{
    const float* A   = (const float*)d_in[0];
    const float* x   = (const float*)d_in[1];
    const float* w1  = (const float*)d_in[2];
    const float* lw1 = (const float*)d_in[3];
    const float* lb1 = (const float*)d_in[4];
    const float* w2  = (const float*)d_in[5];
    const float* lw2 = (const float*)d_in[6];
    const float* lb2 = (const float*)d_in[7];
    const float* gw  = (const float*)d_in[8];
    const float* gb  = (const float*)d_in[9];
    const float* nw  = (const float*)d_in[10];
    const float* nb  = (const float*)d_in[11];
    const float* l3w = (const float*)d_in[12];
    const float* l3b = (const float*)d_in[13];
    const float* l4w = (const float*)d_in[14];
    const float* l4b = (const float*)d_in[15];
    const float* l5w = (const float*)d_in[16];
    const float* l5b = (const float*)d_in[17];
    float* out = (float*)d_out;
    unsigned short* wp = (unsigned short*)d_ws;

    pack_weights<<<104, 512, 0, stream>>>(w1, lw1, w2, lw2, nw, wp);
    fused_kernel<<<SN, 1024, 0, stream>>>(A, x, wp, lb1, lb2, gw, gb, nb,
                                          l3w, l3b, l4w, l4b, l5w, l5b, out);
}

// Round 9
// 114.784 us; speedup vs baseline: 1.1198x; 1.1198x over previous
//
#include <hip/hip_runtime.h>
#include <math.h>

#define SN  512
#define NN  128
#define CIN 32
#define CA  5
#define HH  64
#define YY  96
#define H3  128
#define H4  64
#define EPSF 1e-7f

typedef __attribute__((ext_vector_type(8))) short  bf16x8;
typedef __attribute__((ext_vector_type(4))) float  f32x4;
typedef __attribute__((ext_vector_type(4))) unsigned short us4;

__device__ inline unsigned short f2b(float f) {
    unsigned u = __builtin_bit_cast(unsigned, f);
    return (unsigned short)((u + 0x7FFFu + ((u >> 16) & 1u)) >> 16);
}
__device__ inline float b2f(unsigned short h) {
    unsigned u = ((unsigned)h) << 16;
    return __builtin_bit_cast(float, u);
}
__device__ inline bf16x8 pack8(float4 f0, float4 f1) {
    bf16x8 v;
    v[0]=(short)f2b(f0.x); v[1]=(short)f2b(f0.y); v[2]=(short)f2b(f0.z); v[3]=(short)f2b(f0.w);
    v[4]=(short)f2b(f1.x); v[5]=(short)f2b(f1.y); v[6]=(short)f2b(f1.z); v[7]=(short)f2b(f1.w);
    return v;
}

// PZ: 256 rows (c0..c3 x 64 b) x 128 shorts, XOR-swizzled 16B chunks.
__device__ inline void pz_store4(short* PZ, int row, int colsh, const f32x4& pc) {
    int byo = (colsh*2) ^ ((row & 7) << 4);
    us4 w;
    w[0]=f2b(pc[0]); w[1]=f2b(pc[1]); w[2]=f2b(pc[2]); w[3]=f2b(pc[3]);
    *(us4*)&PZ[row*128 + (byo >> 1)] = w;
}
__device__ inline bf16x8 pz_load8(const short* PZ, int row, int colsh) {
    int byo = (colsh*2) ^ ((row & 7) << 4);
    return *(const bf16x8*)&PZ[row*128 + (byo >> 1)];
}
// PART (bf16): [p][i=16][b=64] with kg-rotation on b for bank spread.
__device__ inline int part_idx(int p, int ir, int col, int kg) {
    return p*1024 + ir*64 + ((col + kg*16) & 63);
}

// ws pack (bf16): W1p [c5][b64][a32] @0 | W2p [c5][b64][a96] @10240 | nwp [b128][a96] @40960
__global__ __launch_bounds__(512) void pack_weights(
    const float* __restrict__ w1, const float* __restrict__ lw1,
    const float* __restrict__ w2, const float* __restrict__ lw2,
    const float* __restrict__ nw, unsigned short* __restrict__ wp)
{
    int t = blockIdx.x*512 + threadIdx.x;
    if (t < 10240) {
        int c = t >> 11, rem = t & 2047, b = rem >> 5, a = rem & 31;
        float v = (c < 4) ? w1[(a*64+b)*4 + c] : lw1[a*64+b];
        wp[t] = f2b(v);
    } else if (t < 40960) {
        int u = t - 10240;
        int c = u / 6144, rem = u % 6144, b = rem / 96, a = rem % 96;
        float v = (c < 4) ? w2[(a*64+b)*4 + c] : lw2[a*64+b];
        wp[t] = f2b(v);
    } else {
        int u = t - 40960;
        int b = u / 96, a = u % 96;
        wp[t] = f2b(nw[a*128 + b]);
    }
}

// pack_A: one block (128 thr, 2 waves) per (s,p-tile): A rows -> PRE-NORMALIZED
// bf16 MFMA A-fragments. pk layout: [(s*8+p)*4+jt][c][lane][8 bf16].
__global__ __launch_bounds__(128) void pack_A(
    const float* __restrict__ A, unsigned short* __restrict__ pk)
{
    __shared__ unsigned short tile[16*520];   // [row16][c*128+j], pad 8
    __shared__ float invL[16][4];
    const int blk = blockIdx.x;               // s*8 + p
    const int tid = threadIdx.x;
    const int h = tid >> 6, lane = tid & 63;
    const int r8 = lane >> 3, l8 = lane & 7;
    const int rr = r8 + 8*h;
    const float* Ab = A + (size_t)blk*16*NN*CA + (size_t)rr*NN*CA;
    unsigned short* tr = tile + rr*520;
    float s0=0.f, s1=0.f, s2=0.f, s3=0.f;
    #pragma unroll
    for (int jt = 0; jt < 4; ++jt) {
        const float* rp = Ab + jt*160 + l8*20;
        float4 q0 = *(const float4*)(rp);
        float4 q1 = *(const float4*)(rp+4);
        float4 q2 = *(const float4*)(rp+8);
        float4 q3 = *(const float4*)(rp+12);
        float4 q4 = *(const float4*)(rp+16);
        const int jb = jt*32 + 4*l8;
        tr[    jb  ] = f2b(q0.x); tr[128+jb  ] = f2b(q0.y);
        tr[256+jb  ] = f2b(q0.z); tr[384+jb  ] = f2b(q0.w);
        tr[    jb+1] = f2b(q1.y); tr[128+jb+1] = f2b(q1.z);
        tr[256+jb+1] = f2b(q1.w); tr[384+jb+1] = f2b(q2.x);
        tr[    jb+2] = f2b(q2.z); tr[128+jb+2] = f2b(q2.w);
        tr[256+jb+2] = f2b(q3.x); tr[384+jb+2] = f2b(q3.y);
        tr[    jb+3] = f2b(q3.w); tr[128+jb+3] = f2b(q4.x);
        tr[256+jb+3] = f2b(q4.y); tr[384+jb+3] = f2b(q4.z);
        s0 += q0.x + q1.y + q2.z + q3.w;
        s1 += q0.y + q1.z + q2.w + q4.x;
        s2 += q0.z + q1.w + q3.x + q4.y;
        s3 += q0.w + q2.x + q3.y + q4.z;
    }
    #pragma unroll
    for (int off = 1; off < 8; off <<= 1) {
        s0 += __shfl_xor(s0, off); s1 += __shfl_xor(s1, off);
        s2 += __shfl_xor(s2, off); s3 += __shfl_xor(s3, off);
    }
    if (l8 == 0) {
        invL[rr][0] = 1.0f/(s0+EPSF); invL[rr][1] = 1.0f/(s1+EPSF);
        invL[rr][2] = 1.0f/(s2+EPSF); invL[rr][3] = 1.0f/(s3+EPSF);
    }
    __syncthreads();
    const int lm = lane & 15, kg = lane >> 4;
    #pragma unroll
    for (int jt = 0; jt < 4; ++jt) {
        #pragma unroll
        for (int cl = 0; cl < 2; ++cl) {
            const int c = 2*h + cl;
            const float iv = invL[lm][c];
            bf16x8 t = *(const bf16x8*)&tile[lm*520 + c*128 + jt*32 + kg*8];
            bf16x8 o;
            #pragma unroll
            for (int q = 0; q < 8; ++q)
                o[q] = (short)f2b(b2f((unsigned short)t[q]) * iv);
            *(bf16x8*)&pk[(((size_t)blk*4 + jt)*4 + c)*512 + lane*8] = o;
        }
    }
}

// Conv stage. Wave (p,h): P-phase h0 -> c{0,1}, h1 -> c{2,3} + c4(linear)->PART;
// main GEMM streams prenormalized A-frags from pk; h1 RMWs PART; h0 combines.
template<int CINY>
__device__ __forceinline__ void conv_core(
    const unsigned short* __restrict__ wp,
    const unsigned short* __restrict__ pkb,
    const float* __restrict__ LB,
    short* PZ, unsigned short* PART,
    bf16x8 y0, bf16x8 y1, bf16x8 y2,
    float (&v)[4][4], int p, int h, int lm, int kg, int lane)
{
    constexpr int K32  = CINY / 32;
    constexpr int WOFF = (CINY == 32) ? 0 : 10240;
    bf16x8 yf[3] = {y0, y1, y2};

    #pragma unroll
    for (int cl = 0; cl < 3; ++cl) {
        if (!h && cl == 2) continue;
        const int c = h ? 2 + cl : cl;
        f32x4 pc[4];
        #pragma unroll
        for (int n = 0; n < 4; ++n) pc[n] = (f32x4){0.f,0.f,0.f,0.f};
        #pragma unroll
        for (int ks = 0; ks < K32; ++ks) {
            #pragma unroll
            for (int n = 0; n < 4; ++n) {
                const bf16x8 bw = *(const bf16x8*)&wp[WOFF + (c*64 + n*16 + lm)*CINY + ks*32 + kg*8];
                pc[n] = __builtin_amdgcn_mfma_f32_16x16x32_bf16(yf[ks], bw, pc[n], 0,0,0);
            }
        }
        if (c < 4) {
            #pragma unroll
            for (int n = 0; n < 4; ++n)
                pz_store4(PZ, c*64 + n*16 + lm, p*16 + kg*4, pc[n]);
        } else {
            #pragma unroll
            for (int n = 0; n < 4; ++n)
                #pragma unroll
                for (int r = 0; r < 4; ++r)
                    PART[part_idx(p, kg*4+r, n*16+lm, kg)] = f2b(pc[n][r]);
        }
    }
    __syncthreads();

    f32x4 acc[2][4];
    #pragma unroll
    for (int cl=0;cl<2;++cl)
        #pragma unroll
        for (int n=0;n<4;++n) acc[cl][n] = (f32x4){0.f,0.f,0.f,0.f};

    #pragma unroll
    for (int jt = 0; jt < 4; ++jt) {
        const bf16x8 A0 = *(const bf16x8*)&pkb[(size_t)((jt*4 + 2*h    )*64 + lane)*8];
        const bf16x8 A1 = *(const bf16x8*)&pkb[(size_t)((jt*4 + 2*h + 1)*64 + lane)*8];
        #pragma unroll
        for (int n = 0; n < 4; ++n) {
            const bf16x8 b0 = pz_load8(PZ, (2*h  )*64 + n*16 + lm, jt*32 + kg*8);
            acc[0][n] = __builtin_amdgcn_mfma_f32_16x16x32_bf16(A0, b0, acc[0][n], 0,0,0);
            const bf16x8 b1 = pz_load8(PZ, (2*h+1)*64 + n*16 + lm, jt*32 + kg*8);
            acc[1][n] = __builtin_amdgcn_mfma_f32_16x16x32_bf16(A1, b1, acc[1][n], 0,0,0);
        }
    }

    if (h) {   // fold channels {2,3} into PART (already holds linear term)
        #pragma unroll
        for (int n=0;n<4;++n)
            #pragma unroll
            for (int r=0;r<4;++r) {
                const int idx = part_idx(p, kg*4+r, n*16+lm, kg);
                PART[idx] = f2b(b2f(PART[idx]) + acc[0][n][r] + acc[1][n][r]);
            }
    }
    __syncthreads();
    if (!h) {  // combine: own {0,1} + PART(c2+c3+linear) + bias, tanh
        #pragma unroll
        for (int n=0;n<4;++n) {
            const float lbv = LB[n*16 + lm];
            #pragma unroll
            for (int r=0;r<4;++r) {
                float vv = lbv + acc[0][n][r] + acc[1][n][r]
                         + b2f(PART[part_idx(p, kg*4+r, n*16+lm, kg)]);
                v[n][r] = tanhf(vv);
            }
        }
    }
}

__global__ __launch_bounds__(1024, 8) void fused_kernel(
    const float* __restrict__ x,
    const unsigned short* __restrict__ wp,
    const unsigned short* __restrict__ pk,
    const float* __restrict__ lb1, const float* __restrict__ lb2,
    const float* __restrict__ gw, const float* __restrict__ gb,
    const float* __restrict__ nb,
    const float* __restrict__ l3w, const float* __restrict__ l3b,
    const float* __restrict__ l4w, const float* __restrict__ l4b,
    const float* __restrict__ l5w, const float* __restrict__ l5b,
    float* __restrict__ out)
{
    __shared__ __align__(16) char smem[81920];
    short* PZ = (short*)smem;                               // 256x128 sh = 65536 B
    unsigned short* PART = (unsigned short*)(smem + 65536); // 8192 sh = 16384 B
    short* H1  = (short*)smem;                              // [128][72] (PZ alias)
    short* xcb = (short*)smem;                              // [128][104] (PZ alias)
    float* part = (float*)(smem + 65536);                   // [16][128] f32 (PART alias)
    float* gate = (float*)(smem + 65536 + 8192);
    float* red  = (float*)(smem + 65536 + 8704);
    float* tmpv = (float*)(smem + 65536 + 9216);

    const int s = blockIdx.x, tid = threadIdx.x;
    const int wave = tid>>6, lane = tid&63, lm = lane&15, kg = lane>>4;
    const int p = wave >> 1, h = wave & 1;
    const float* xg = x + (size_t)s*NN*CIN;
    const unsigned short* pkb = pk + (size_t)(s*8 + p)*16*512;

    const int jrow = p*16 + lm;
    bf16x8 xfrag;
    {
        float4 f0 = *(const float4*)(xg + jrow*CIN + kg*8);
        float4 f1 = *(const float4*)(xg + jrow*CIN + kg*8 + 4);
        xfrag = pack8(f0, f1);
    }

    // ===== conv1 =====
    float v[4][4];
    conv_core<CIN>(wp, pkb, lb1, PZ, PART, xfrag, xfrag, xfrag,
                   v, p, h, lm, kg, lane);
    if (!h) {  // h1 -> H1 (PZ region dead: all PZ reads finished before last bar)
        #pragma unroll
        for (int n=0;n<4;++n)
            #pragma unroll
            for (int r=0;r<4;++r)
                H1[(p*16 + kg*4 + r)*72 + n*16 + lm] = (short)f2b(v[n][r]);
    }
    __syncthreads();   // H1 visible

    // ===== conv2 =====
    {
        bf16x8 h0f = *(const bf16x8*)&H1[jrow*72 + kg*8];
        bf16x8 h1f = *(const bf16x8*)&H1[jrow*72 + 32 + kg*8];
        __syncthreads();   // H1 reads done -> PZ writable
        conv_core<YY>(wp, pkb, lb2, PZ, PART, h0f, h1f, xfrag,
                      v, p, h, lm, kg, lane);
    }

    // ===== pool + head =====
    if (!h) {
        #pragma unroll
        for (int n=0;n<4;++n)
            #pragma unroll
            for (int r=0;r<4;++r)
                xcb[(p*16 + kg*4 + r)*104 + n*16 + lm] = (short)f2b(v[n][r]);
    }
    for (int t = tid; t < NN*CIN; t += 1024)
        xcb[(t>>5)*104 + 64 + (t&31)] = (short)f2b(xg[t]);
    __syncthreads();

    // gate logits: 8 threads per node
    {
        const int i = tid >> 3, t8 = tid & 7;
        float z = 0.f;
        #pragma unroll
        for (int q = 0; q < 12; ++q) {
            const int a = t8*12 + q;
            z += b2f((unsigned short)xcb[i*104 + a]) * gw[a];
        }
        z += __shfl_xor(z, 1); z += __shfl_xor(z, 2); z += __shfl_xor(z, 4);
        if (t8 == 0) red[i] = z + gb[0];
    }
    __syncthreads();
    if (wave == 0) {   // softmax over 128 nodes, one wave
        float v0 = red[lane], v1 = red[lane + 64];
        float m = fmaxf(v0, v1);
        #pragma unroll
        for (int off = 32; off > 0; off >>= 1) m = fmaxf(m, __shfl_xor(m, off));
        float e0 = expf(v0 - m), e1 = expf(v1 - m);
        float ssum = e0 + e1;
        #pragma unroll
        for (int off = 32; off > 0; off >>= 1) ssum += __shfl_xor(ssum, off);
        gate[lane] = e0 / ssum; gate[lane + 64] = e1 / ssum;
    }
    __syncthreads();

    // pooled GEMM: i-tile = p, halves split the 8 column tiles
    {
        f32x4 pacc[4];
        #pragma unroll
        for (int nt=0;nt<4;++nt) pacc[nt] = (f32x4){0.f,0.f,0.f,0.f};
        #pragma unroll
        for (int ks=0;ks<3;++ks) {
            const bf16x8 afp = *(const bf16x8*)&xcb[(p*16+lm)*104 + ks*32 + kg*8];
            #pragma unroll
            for (int nt=0;nt<4;++nt) {
                const int ntg = h*4 + nt;
                const bf16x8 bfp = *(const bf16x8*)&wp[40960 + (ntg*16+lm)*96 + ks*32 + kg*8];
                pacc[nt] = __builtin_amdgcn_mfma_f32_16x16x32_bf16(afp, bfp, pacc[nt], 0,0,0);
            }
        }
        #pragma unroll
        for (int nt=0;nt<4;++nt) {
            const int ntg = h*4 + nt;
            const float nbv = nb[ntg*16+lm];
            float pv = 0.f;
            #pragma unroll
            for (int r=0;r<4;++r)
                pv += gate[p*16 + kg*4 + r] * tanhf(pacc[nt][r] + nbv);
            pv += __shfl_xor(pv, 16);
            pv += __shfl_xor(pv, 32);
            if (lane < 16) part[wave*128 + ntg*16 + lm] = pv;
        }
    }
    __syncthreads();
    if (tid < H3) {
        // wave (p,h) wrote only columns [h*64, h*64+64) of its part row.
        const int ht = tid >> 6;
        float pooled = 0.f;
        #pragma unroll
        for (int pp = 0; pp < 8; ++pp) pooled += part[(pp*2 + ht)*128 + tid];
        tmpv[tid] = tanhf(pooled);                 // h3
    }
    __syncthreads();
    if (tid < H3) {
        float a4 = l3b[tid];
        for (int aa = 0; aa < H3; ++aa) a4 += tmpv[aa] * l3w[aa*H3 + tid];
        red[tid] = tanhf(a4);                      // h4
    }
    __syncthreads();
    if (tid < H4) {
        float a5 = l4b[tid];
        for (int aa = 0; aa < H3; ++aa) a5 += red[aa] * l4w[aa*H4 + tid];
        gate[tid] = tanhf(a5);                     // h5
    }
    __syncthreads();
    if (tid == 0) {
        float zo = l5b[0];
        for (int aa = 0; aa < H4; ++aa) zo += gate[aa] * l5w[aa];
        out[s] = 1.0f / (1.0f + expf(-zo));
    }
}

extern "C" void kernel_launch(void* const* d_in, const int* in_sizes, int n_in,
                              void* d_out, int out_size, void* d_ws, size_t ws_size,
                              hipStream_t stream)
{
    const float* A   = (const float*)d_in[0];
    const float* x   = (const float*)d_in[1];
    const float* w1  = (const float*)d_in[2];
    const float* lw1 = (const float*)d_in[3];
    const float* lb1 = (const float*)d_in[4];
    const float* w2  = (const float*)d_in[5];
    const float* lw2 = (const float*)d_in[6];
    const float* lb2 = (const float*)d_in[7];
    const float* gw  = (const float*)d_in[8];
    const float* gb  = (const float*)d_in[9];
    const float* nw  = (const float*)d_in[10];
    const float* nb  = (const float*)d_in[11];
    const float* l3w = (const float*)d_in[12];
    const float* l3b = (const float*)d_in[13];
    const float* l4w = (const float*)d_in[14];
    const float* l4b = (const float*)d_in[15];
    const float* l5w = (const float*)d_in[16];
    const float* l5b = (const float*)d_in[17];
    float* out = (float*)d_out;
    unsigned short* wp = (unsigned short*)d_ws;                     // 106,496 B
    unsigned short* pk = (unsigned short*)((char*)d_ws + 131072);   // 64 MiB

    pack_weights<<<104, 512, 0, stream>>>(w1, lw1, w2, lw2, nw, wp);
    pack_A<<<SN*8, 128, 0, stream>>>(A, pk);
    fused_kernel<<<SN, 1024, 0, stream>>>(x, wp, pk, lb1, lb2, gw, gb, nb,
                                          l3w, l3b, l4w, l4b, l5w, l5b, out);
}